// Round 1
// baseline (450.483 us; speedup 1.0000x reference)
//
#include <hip/hip_runtime.h>
#include <math.h>

#define NPTS 2048
#define BATCH 16
#define KNN 16
#define HID 128

// ---------------------------------------------------------------------------
// kNN: one wave per row. 32 candidates per lane held as double keys
// key = (double)d2 * 2^42 + idx  (exact, order == (d2, idx) lexicographic).
// 16 rounds of wave argmin; each round's scan also "kills" the previous
// winner (equality match) and records its index. d2 computed with
// non-contracted fp32 ops to match numpy: (sqi + sqj) - 2*dot.
// ---------------------------------------------------------------------------
__global__ __launch_bounds__(256) void knn_kernel(const float* __restrict__ pc,
                                                  int* __restrict__ nbr)
{
    __shared__ float xs[NPTS], ys[NPTS], zs[NPTS], sq[NPTS];
    const int b = blockIdx.x >> 9;              // 512 blocks per batch
    const int row_base = (blockIdx.x & 511) << 2;
    const float* p = pc + (size_t)b * NPTS * 3;

    for (int t = threadIdx.x; t < NPTS; t += 256) {
        float x = p[t * 3 + 0], y = p[t * 3 + 1], z = p[t * 3 + 2];
        xs[t] = x; ys[t] = y; zs[t] = z;
        sq[t] = __fadd_rn(__fadd_rn(__fmul_rn(x, x), __fmul_rn(y, y)), __fmul_rn(z, z));
    }
    __syncthreads();

    const int wave = threadIdx.x >> 6;
    const int lane = threadIdx.x & 63;
    const int i = row_base + wave;
    const float xi = xs[i], yi = ys[i], zi = zs[i], sqi = sq[i];

    double key[32];
    #pragma unroll
    for (int t = 0; t < 32; ++t) {
        int j = t * 64 + lane;                  // coalesced LDS, conflict-free
        float dot = __fadd_rn(__fadd_rn(__fmul_rn(xi, xs[j]), __fmul_rn(yi, ys[j])),
                              __fmul_rn(zi, zs[j]));
        float d2 = __fsub_rn(__fadd_rn(sqi, sq[j]), __fmul_rn(2.0f, dot));
        key[t] = (double)d2 * 4398046511104.0 /* 2^42 */ + (double)j;
    }

    const double HUGE_K = 1e300;
    double wprev = -1e300;                      // matches nothing in round 0
    unsigned my_nbr = 0;

    #pragma unroll 1
    for (int r = 0; r < KNN; ++r) {
        double lmin = HUGE_K;
        unsigned myidx = 0xFFFFFFFFu;
        #pragma unroll
        for (int t = 0; t < 32; ++t) {
            double kk = key[t];
            bool hit = (kk == wprev);           // previous round's winner slot
            if (hit) myidx = (unsigned)(t * 64 + lane);
            kk = hit ? HUGE_K : kk;
            key[t] = kk;
            lmin = fmin(lmin, kk);
        }
        // broadcast previous winner's index to all lanes (min over wave)
        #pragma unroll
        for (int off = 32; off; off >>= 1) {
            unsigned o = __shfl_xor(myidx, off, 64);
            myidx = (o < myidx) ? o : myidx;
        }
        if (r > 0 && lane == r - 1) my_nbr = myidx;
        // wave min of keys = this round's winner
        #pragma unroll
        for (int off = 32; off; off >>= 1) {
            double o = __shfl_xor(lmin, off, 64);
            lmin = fmin(lmin, o);
        }
        wprev = lmin;
    }
    // recover the last round's winner index
    {
        unsigned myidx = 0xFFFFFFFFu;
        #pragma unroll
        for (int t = 0; t < 32; ++t)
            if (key[t] == wprev) myidx = (unsigned)(t * 64 + lane);
        #pragma unroll
        for (int off = 32; off; off >>= 1) {
            unsigned o = __shfl_xor(myidx, off, 64);
            myidx = (o < myidx) ? o : myidx;
        }
        if (lane == KNN - 1) my_nbr = myidx;
    }
    if (lane < KNN)
        nbr[((size_t)b * NPTS + i) * KNN + lane] = (int)my_nbr;
}

// ---------------------------------------------------------------------------
// Layer 1: 3 -> 128, fused gather+matvec+bias+relu. One block per point.
// ---------------------------------------------------------------------------
__global__ __launch_bounds__(128) void layer1_kernel(
    const float* __restrict__ pc, const int* __restrict__ nbr,
    const float* __restrict__ W1r, const float* __restrict__ b1,
    const float* __restrict__ W1s, float* __restrict__ x1)
{
    __shared__ float agg[3], xi[3];
    __shared__ float nb[KNN][3];
    const int p = blockIdx.x;                   // global point id
    const int b = p >> 11;
    const float* pcb = pc + ((size_t)b << 11) * 3;
    const int h = threadIdx.x;
    if (h < KNN) {
        int j = nbr[(size_t)p * KNN + h];
        nb[h][0] = pcb[j * 3 + 0];
        nb[h][1] = pcb[j * 3 + 1];
        nb[h][2] = pcb[j * 3 + 2];
    }
    if (h >= KNN && h < KNN + 3) {
        int c = h - KNN;
        xi[c] = pc[(size_t)p * 3 + c];
    }
    __syncthreads();
    if (h < 3) {
        float s = 0.f;
        #pragma unroll
        for (int t = 0; t < KNN; ++t) s += nb[t][h];
        agg[h] = s;
    }
    __syncthreads();
    float acc = b1[h];
    #pragma unroll
    for (int c = 0; c < 3; ++c)
        acc += W1r[h * 3 + c] * agg[c] + W1s[h * 3 + c] * xi[c];
    x1[(size_t)p * HID + h] = fmaxf(acc, 0.f);
}

// ---------------------------------------------------------------------------
// Gather-sum: agg[p][c] = sum_{t<16} x[b, nbr[p][t], c]. One thread per (p,c).
// ---------------------------------------------------------------------------
__global__ __launch_bounds__(256) void gather_kernel(
    const float* __restrict__ x, const int* __restrict__ nbr,
    float* __restrict__ agg)
{
    int gid = blockIdx.x * 256 + threadIdx.x;   // < 32768*128 = 4.19M
    int p = gid >> 7;
    int c = gid & 127;
    int b = p >> 11;
    const float* xb = x + (((size_t)b << 11) * HID);
    const int* nr = nbr + (size_t)p * KNN;
    float s = 0.f;
    #pragma unroll
    for (int t = 0; t < KNN; ++t)
        s += xb[(size_t)nr[t] * HID + c];
    agg[(size_t)p * HID + c] = s;
}

// ---------------------------------------------------------------------------
// GraphConv 128->128: out[p][h] = Wr@agg_p + Ws@x_p + b (+relu).
// Block = 256 threads, 16 points. Thread (s,h): s picks K-half (agg vs x),
// accumulates 16 points in registers; halves summed via LDS. Weights read
// from global (L1/L2 resident, 128 KB reused over 16 points). A-tile in LDS,
// read as float4 broadcasts. Output may alias input x: each block reads only
// its own 16 rows (staged to LDS) before writing them -> safe in-place.
// ---------------------------------------------------------------------------
template <bool RELU>
__global__ __launch_bounds__(256) void conv_kernel(
    const float* __restrict__ agg, const float* __restrict__ x,
    const float* __restrict__ Wr, const float* __restrict__ bias,
    const float* __restrict__ Ws, float* __restrict__ out)
{
    __shared__ __align__(16) float At[2][HID][20];   // [half][c][point], pad 20
    __shared__ float red[HID][17];
    const int p0 = blockIdx.x * 16;
    const int s = threadIdx.x >> 7;
    const int h = threadIdx.x & 127;

    for (int e = threadIdx.x; e < 2 * 16 * HID; e += 256) {
        int which = e >> 11;                    // 0: agg, 1: x
        int pp = (e >> 7) & 15;
        int c = e & 127;
        const float* src = which ? x : agg;
        At[which][c][pp] = src[(size_t)(p0 + pp) * HID + c];
    }
    __syncthreads();

    const float* W = s ? Ws : Wr;
    float acc[16];
    #pragma unroll
    for (int q = 0; q < 16; ++q) acc[q] = 0.f;

    const float4* W4 = (const float4*)(W + (size_t)h * HID);
    #pragma unroll 4
    for (int c4 = 0; c4 < 32; ++c4) {
        float4 wv = W4[c4];
        float wj[4] = {wv.x, wv.y, wv.z, wv.w};
        #pragma unroll
        for (int j = 0; j < 4; ++j) {
            int c = c4 * 4 + j;
            const float4* a4 = (const float4*)&At[s][c][0];
            #pragma unroll
            for (int pt = 0; pt < 4; ++pt) {
                float4 av = a4[pt];             // broadcast: all lanes same addr
                acc[pt * 4 + 0] += wj[j] * av.x;
                acc[pt * 4 + 1] += wj[j] * av.y;
                acc[pt * 4 + 2] += wj[j] * av.z;
                acc[pt * 4 + 3] += wj[j] * av.w;
            }
        }
    }

    if (s == 0) {
        #pragma unroll
        for (int q = 0; q < 16; ++q) red[h][q] = acc[q];
    }
    __syncthreads();
    if (s == 1) {
        float bh = bias[h];
        #pragma unroll
        for (int q = 0; q < 16; ++q) {
            float v = acc[q] + red[h][q] + bh;
            if (RELU) v = fmaxf(v, 0.f);
            out[(size_t)(p0 + q) * HID + h] = v;   // coalesced over h
        }
    }
}

// ---------------------------------------------------------------------------
extern "C" void kernel_launch(void* const* d_in, const int* in_sizes, int n_in,
                              void* d_out, int out_size, void* d_ws, size_t ws_size,
                              hipStream_t stream)
{
    const float* pc  = (const float*)d_in[0];
    const float* W1r = (const float*)d_in[1];
    const float* b1  = (const float*)d_in[2];
    const float* W1s = (const float*)d_in[3];
    const float* W2r = (const float*)d_in[4];
    const float* b2  = (const float*)d_in[5];
    const float* W2s = (const float*)d_in[6];
    const float* W3r = (const float*)d_in[7];
    const float* b3  = (const float*)d_in[8];
    const float* W3s = (const float*)d_in[9];
    float* out = (float*)d_out;

    char* ws = (char*)d_ws;
    int*   nbr  = (int*)ws;                                   // 2 MB
    float* xbuf = (float*)(ws + (size_t)2 * 1024 * 1024);     // 16.78 MB
    float* aggb = (float*)(ws + (size_t)(2 * 1024 * 1024) + (size_t)BATCH * NPTS * HID * 4);

    const int NPOINTS = BATCH * NPTS;                         // 32768

    knn_kernel<<<NPOINTS / 4, 256, 0, stream>>>(pc, nbr);
    layer1_kernel<<<NPOINTS, 128, 0, stream>>>(pc, nbr, W1r, b1, W1s, xbuf);

    gather_kernel<<<NPOINTS * HID / 256, 256, 0, stream>>>(xbuf, nbr, aggb);
    conv_kernel<true><<<NPOINTS / 16, 256, 0, stream>>>(aggb, xbuf, W2r, b2, W2s, xbuf);

    gather_kernel<<<NPOINTS * HID / 256, 256, 0, stream>>>(xbuf, nbr, aggb);
    conv_kernel<false><<<NPOINTS / 16, 256, 0, stream>>>(aggb, xbuf, W3r, b3, W3s, out);
}

// Round 2
// 266.315 us; speedup vs baseline: 1.6915x; 1.6915x over previous
//
#include <hip/hip_runtime.h>
#include <math.h>

#define NPTS 2048
#define BATCH 16
#define KNN 16
#define HID 128
#define RPB 8          // rows (queries) per block = waves per block
#define CAP 128        // compacted-candidate capacity per wave

// ---------------------------------------------------------------------------
// kNN via threshold selection. One wave per query row.
// key = float_bits(d2 + 16.0f)  (monotone: d2 >= -1e-6 always, so d2+16 > 0).
// Neighbor ORDER does not matter downstream (only summed), so we emit the
// set of the 16 smallest keys, tie-broken by candidate index (matches
// lax.top_k stability up to key-quantization ties).
// ---------------------------------------------------------------------------
__global__ __launch_bounds__(512) void knn_kernel(const float* __restrict__ pc,
                                                  int* __restrict__ nbr)
{
    __shared__ __align__(16) float4 pts[NPTS];        // x,y,z,|p|^2  (32 KB)
    __shared__ unsigned ckey[RPB][CAP];               // 4 KB
    __shared__ unsigned cidx[RPB][CAP];               // 4 KB

    const int b = blockIdx.x >> 8;                    // 256 blocks per batch
    const int rblk = blockIdx.x & 255;
    const float* p = pc + (size_t)b * NPTS * 3;

    for (int t = threadIdx.x; t < NPTS; t += 512) {
        float x = p[t * 3 + 0], y = p[t * 3 + 1], z = p[t * 3 + 2];
        pts[t] = make_float4(x, y, z, x * x + y * y + z * z);
    }
    __syncthreads();

    const int w = threadIdx.x >> 6;
    const int lane = threadIdx.x & 63;
    const int i = rblk * RPB + w;                     // query row in batch
    const float4 pi = pts[i];

    // ---- phase 1: 32 candidate keys per lane (registers, fully unrolled) --
    unsigned key[32];
    #pragma unroll
    for (int t = 0; t < 32; ++t) {
        float4 c = pts[t * 64 + lane];
        float dot = fmaf(pi.x, c.x, fmaf(pi.y, c.y, pi.z * c.z));
        float d2 = fmaf(-2.0f, dot, pi.w + c.w);
        key[t] = __float_as_uint(d2 + 16.0f);
    }

    // ---- phase 2: per-lane min -------------------------------------------
    unsigned km = 0xFFFFFFFFu;
    #pragma unroll
    for (int t = 0; t < 32; ++t) km = min(km, key[t]);

    // ---- phase 3: bitonic sort of 64 lane-mins; T0 = 16th smallest -------
    unsigned v = km;
    #pragma unroll
    for (int k = 2; k <= 64; k <<= 1) {
        #pragma unroll
        for (int j = k >> 1; j > 0; j >>= 1) {
            unsigned o = (unsigned)__shfl_xor((int)v, j, 64);
            bool up = ((lane & k) == 0);
            bool lower = ((lane & j) == 0);
            unsigned mn = min(v, o), mx = max(v, o);
            v = (up == lower) ? mn : mx;
        }
    }
    const unsigned T0 = (unsigned)__shfl((int)v, 15, 64);
    // >=16 candidates have key <= T0 (the 16 smallest lane-mins themselves),
    // and T0 >= true 16th-smallest key  =>  {key <= T0} superset of top-16.

    // ---- phase 4: ballot-compact candidates <= T0 into LDS ---------------
    unsigned base = 0;
    #pragma unroll 1
    for (int t = 0; t < 32; ++t) {
        bool pred = key[t] <= T0;
        unsigned long long mask = __ballot(pred);
        if (mask) {
            unsigned prefix = __builtin_amdgcn_mbcnt_hi(
                (unsigned)(mask >> 32),
                __builtin_amdgcn_mbcnt_lo((unsigned)mask, 0));
            unsigned pos = base + prefix;
            if (pred && pos < CAP) {
                ckey[w][pos] = key[t];
                cidx[w][pos] = (unsigned)(t * 64 + lane);
            }
            base += (unsigned)__popcll(mask);
        }
    }
    __threadfence_block();
    const int m = (int)base;

    int* out = nbr + ((size_t)b * NPTS + i) * KNN;

    if (m <= CAP) {
        // ---- phase 5: rank-count the m survivors; rank<16 -> output slot -
        unsigned k0 = (lane < m) ? ckey[w][lane] : 0xFFFFFFFFu;
        unsigned k1 = (lane + 64 < m) ? ckey[w][lane + 64] : 0xFFFFFFFFu;
        int r0 = 0, r1 = 0;
        if (m <= 64) {
            #pragma unroll 1
            for (int jj = 0; jj < m; ++jj) {
                unsigned kj = ckey[w][jj];
                r0 += (kj < k0) || (kj == k0 && jj < lane);
            }
        } else {
            #pragma unroll 1
            for (int jj = 0; jj < m; ++jj) {
                unsigned kj = ckey[w][jj];
                r0 += (kj < k0) || (kj == k0 && jj < lane);
                r1 += (kj < k1) || (kj == k1 && jj < lane + 64);
            }
        }
        if (lane < m && r0 < KNN) out[r0] = (int)cidx[w][lane];
        if (lane + 64 < m && r1 < KNN) out[r1] = (int)cidx[w][lane + 64];
    } else {
        // ---- fallback (never taken w/ random data, kept for correctness):
        // exact bit-search for T = 16th smallest key over the wave.
        unsigned T = 0;
        #pragma unroll 1
        for (int bit = 31; bit >= 0; --bit) {
            unsigned trial = T | (1u << bit);
            int cnt = 0;
            #pragma unroll
            for (int t = 0; t < 32; ++t) cnt += (key[t] < trial);
            #pragma unroll
            for (int off = 32; off; off >>= 1)
                cnt += __shfl_xor(cnt, off, 64);
            if (cnt < KNN) T = trial;
        }
        unsigned bs = 0;
        #pragma unroll 1
        for (int t = 0; t < 32; ++t) {               // strictly-below first
            bool p1 = key[t] < T;
            unsigned long long mask = __ballot(p1);
            if (mask) {
                unsigned prefix = __builtin_amdgcn_mbcnt_hi(
                    (unsigned)(mask >> 32),
                    __builtin_amdgcn_mbcnt_lo((unsigned)mask, 0));
                if (p1) out[bs + prefix] = t * 64 + lane;
                bs += (unsigned)__popcll(mask);
            }
        }
        #pragma unroll 1
        for (int t = 0; t < 32 && bs < KNN; ++t) {   // fill ties == T
            bool p2 = key[t] == T;
            unsigned long long mask = __ballot(p2);
            if (mask) {
                unsigned prefix = __builtin_amdgcn_mbcnt_hi(
                    (unsigned)(mask >> 32),
                    __builtin_amdgcn_mbcnt_lo((unsigned)mask, 0));
                unsigned pos = bs + prefix;
                if (p2 && pos < KNN) out[pos] = t * 64 + lane;
                bs += (unsigned)__popcll(mask);
            }
        }
    }
}

// ---------------------------------------------------------------------------
// Layer 1: 3 -> 128, fused gather+matvec+bias+relu. One block per point.
// ---------------------------------------------------------------------------
__global__ __launch_bounds__(128) void layer1_kernel(
    const float* __restrict__ pc, const int* __restrict__ nbr,
    const float* __restrict__ W1r, const float* __restrict__ b1,
    const float* __restrict__ W1s, float* __restrict__ x1)
{
    __shared__ float agg[3], xi[3];
    __shared__ float nb[KNN][3];
    const int p = blockIdx.x;                   // global point id
    const int b = p >> 11;
    const float* pcb = pc + ((size_t)b << 11) * 3;
    const int h = threadIdx.x;
    if (h < KNN) {
        int j = nbr[(size_t)p * KNN + h];
        nb[h][0] = pcb[j * 3 + 0];
        nb[h][1] = pcb[j * 3 + 1];
        nb[h][2] = pcb[j * 3 + 2];
    }
    if (h >= KNN && h < KNN + 3) {
        int c = h - KNN;
        xi[c] = pc[(size_t)p * 3 + c];
    }
    __syncthreads();
    if (h < 3) {
        float s = 0.f;
        #pragma unroll
        for (int t = 0; t < KNN; ++t) s += nb[t][h];
        agg[h] = s;
    }
    __syncthreads();
    float acc = b1[h];
    #pragma unroll
    for (int c = 0; c < 3; ++c)
        acc += W1r[h * 3 + c] * agg[c] + W1s[h * 3 + c] * xi[c];
    x1[(size_t)p * HID + h] = fmaxf(acc, 0.f);
}

// ---------------------------------------------------------------------------
// Gather-sum: agg[p][c] = sum_{t<16} x[b, nbr[p][t], c]. One thread per (p,c).
// ---------------------------------------------------------------------------
__global__ __launch_bounds__(256) void gather_kernel(
    const float* __restrict__ x, const int* __restrict__ nbr,
    float* __restrict__ agg)
{
    int gid = blockIdx.x * 256 + threadIdx.x;   // < 32768*128 = 4.19M
    int p = gid >> 7;
    int c = gid & 127;
    int b = p >> 11;
    const float* xb = x + (((size_t)b << 11) * HID);
    const int* nr = nbr + (size_t)p * KNN;
    float s = 0.f;
    #pragma unroll
    for (int t = 0; t < KNN; ++t)
        s += xb[(size_t)nr[t] * HID + c];
    agg[(size_t)p * HID + c] = s;
}

// ---------------------------------------------------------------------------
// GraphConv 128->128: out[p][h] = Wr@agg_p + Ws@x_p + b (+relu).
// Block = 256 threads, 16 points. Safe in-place (reads own rows to LDS first).
// ---------------------------------------------------------------------------
template <bool RELU>
__global__ __launch_bounds__(256) void conv_kernel(
    const float* __restrict__ agg, const float* __restrict__ x,
    const float* __restrict__ Wr, const float* __restrict__ bias,
    const float* __restrict__ Ws, float* __restrict__ out)
{
    __shared__ __align__(16) float At[2][HID][20];   // [half][c][point], pad 20
    __shared__ float red[HID][17];
    const int p0 = blockIdx.x * 16;
    const int s = threadIdx.x >> 7;
    const int h = threadIdx.x & 127;

    for (int e = threadIdx.x; e < 2 * 16 * HID; e += 256) {
        int which = e >> 11;                    // 0: agg, 1: x
        int pp = (e >> 7) & 15;
        int c = e & 127;
        const float* src = which ? x : agg;
        At[which][c][pp] = src[(size_t)(p0 + pp) * HID + c];
    }
    __syncthreads();

    const float* W = s ? Ws : Wr;
    float acc[16];
    #pragma unroll
    for (int q = 0; q < 16; ++q) acc[q] = 0.f;

    const float4* W4 = (const float4*)(W + (size_t)h * HID);
    #pragma unroll 4
    for (int c4 = 0; c4 < 32; ++c4) {
        float4 wv = W4[c4];
        float wj[4] = {wv.x, wv.y, wv.z, wv.w};
        #pragma unroll
        for (int j = 0; j < 4; ++j) {
            int c = c4 * 4 + j;
            const float4* a4 = (const float4*)&At[s][c][0];
            #pragma unroll
            for (int pt = 0; pt < 4; ++pt) {
                float4 av = a4[pt];             // broadcast: all lanes same addr
                acc[pt * 4 + 0] += wj[j] * av.x;
                acc[pt * 4 + 1] += wj[j] * av.y;
                acc[pt * 4 + 2] += wj[j] * av.z;
                acc[pt * 4 + 3] += wj[j] * av.w;
            }
        }
    }

    if (s == 0) {
        #pragma unroll
        for (int q = 0; q < 16; ++q) red[h][q] = acc[q];
    }
    __syncthreads();
    if (s == 1) {
        float bh = bias[h];
        #pragma unroll
        for (int q = 0; q < 16; ++q) {
            float v = acc[q] + red[h][q] + bh;
            if (RELU) v = fmaxf(v, 0.f);
            out[(size_t)(p0 + q) * HID + h] = v;   // coalesced over h
        }
    }
}

// ---------------------------------------------------------------------------
extern "C" void kernel_launch(void* const* d_in, const int* in_sizes, int n_in,
                              void* d_out, int out_size, void* d_ws, size_t ws_size,
                              hipStream_t stream)
{
    const float* pc  = (const float*)d_in[0];
    const float* W1r = (const float*)d_in[1];
    const float* b1  = (const float*)d_in[2];
    const float* W1s = (const float*)d_in[3];
    const float* W2r = (const float*)d_in[4];
    const float* b2  = (const float*)d_in[5];
    const float* W2s = (const float*)d_in[6];
    const float* W3r = (const float*)d_in[7];
    const float* b3  = (const float*)d_in[8];
    const float* W3s = (const float*)d_in[9];
    float* out = (float*)d_out;

    char* ws = (char*)d_ws;
    int*   nbr  = (int*)ws;                                   // 2 MB
    float* xbuf = (float*)(ws + (size_t)2 * 1024 * 1024);     // 16.78 MB
    float* aggb = (float*)(ws + (size_t)(2 * 1024 * 1024) + (size_t)BATCH * NPTS * HID * 4);

    const int NPOINTS = BATCH * NPTS;                         // 32768

    knn_kernel<<<NPOINTS / RPB, 512, 0, stream>>>(pc, nbr);
    layer1_kernel<<<NPOINTS, 128, 0, stream>>>(pc, nbr, W1r, b1, W1s, xbuf);

    gather_kernel<<<NPOINTS * HID / 256, 256, 0, stream>>>(xbuf, nbr, aggb);
    conv_kernel<true><<<NPOINTS / 16, 256, 0, stream>>>(aggb, xbuf, W2r, b2, W2s, xbuf);

    gather_kernel<<<NPOINTS * HID / 256, 256, 0, stream>>>(xbuf, nbr, aggb);
    conv_kernel<false><<<NPOINTS / 16, 256, 0, stream>>>(aggb, xbuf, W3r, b3, W3s, out);
}